// Round 12
// baseline (159.732 us; speedup 1.0000x reference)
//
#include <hip/hip_runtime.h>
#include <hip/hip_bf16.h>
#include <cmath>

using f32x4 = __attribute__((ext_vector_type(4))) float;
using s16x8 = __attribute__((ext_vector_type(8))) short;
using u16x4 = __attribute__((ext_vector_type(4))) unsigned short;

__device__ __forceinline__ float bf2f(unsigned short u){
  union { unsigned int i; float f; } v; v.i = ((unsigned int)u) << 16; return v.f;
}
__device__ __forceinline__ unsigned short f2bf(float f){
  union { float f; unsigned int i; } v; v.f = f;
  return (unsigned short)((v.i + 0x7FFFu + ((v.i >> 16) & 1u)) >> 16);
}

#define GLDS16(g, l) __builtin_amdgcn_global_load_lds( \
    (const __attribute__((address_space(1))) unsigned int*)(g), \
    (__attribute__((address_space(3))) unsigned int*)(l), 16, 0, 0)

// ---------------- prep: bf16 conversions + cls passthrough ----------------
__global__ void k_prep(const float* __restrict__ Wd, const float* __restrict__ Wu,
                       const float* __restrict__ Wt, const float* __restrict__ Wf,
                       const float* __restrict__ Ap, const float* __restrict__ Bp,
                       const int* __restrict__ layerp, const float* __restrict__ x,
                       float* __restrict__ out,
                       unsigned short* __restrict__ Wdb, unsigned short* __restrict__ Wub,
                       unsigned short* __restrict__ Wtb, unsigned short* __restrict__ WB,
                       unsigned short* __restrict__ Ab, unsigned short* __restrict__ Blb){
  int idx = blockIdx.x * 256 + threadIdx.x;
  switch (blockIdx.y){
    case 0: if (idx < 24576)  Wdb[idx] = f2bf(Wd[idx]); break;
    case 1: if (idx < 73728)  Wub[idx] = f2bf(Wu[idx]); break;
    case 2: if (idx < 589824) Wtb[idx] = f2bf(Wt[idx]); break;
    case 3: if (idx < 688128){
      int n = idx / 896, c = idx - n * 896;
      WB[idx] = (c < 768) ? f2bf(Wf[n * 768 + c]) : (unsigned short)0;
    } break;
    case 4: if (idx < 28672){
      int r = idx >> 8;
      Ab[idx] = (r < 100) ? f2bf(Ap[idx]) : (unsigned short)0;
    } break;
    case 5: if (idx < 65536) Blb[idx] = f2bf(Bp[(long)(*layerp) * 65536 + idx]); break;
    case 6: if (idx < 24576) out[idx] = x[idx]; break;   // cls passthrough
  }
}

// ---------------- generic 1-wave MFMA mini-GEMM (tokens = A @ Bf) ----------------
template<int EPI>
__global__ __launch_bounds__(64) void k_mm(const unsigned short* __restrict__ A, int lda,
    const unsigned short* __restrict__ B, int ldb, int K,
    const float* __restrict__ bias, unsigned short* __restrict__ out, int ldo){
  int l = threadIdx.x, l15 = l & 15, lhi = l >> 4;
  int m0 = blockIdx.x * 16, n0 = blockIdx.y * 16;
  f32x4 acc = (f32x4)0.0f;
  #pragma unroll 4
  for (int k0 = 0; k0 < K; k0 += 32){
    s16x8 a = *(const s16x8*)(A + (long)(m0 + l15) * lda + k0 + lhi * 8);
    s16x8 b = *(const s16x8*)(B + (long)(n0 + l15) * ldb + k0 + lhi * 8);
    acc = __builtin_amdgcn_mfma_f32_16x16x32_bf16(a, b, acc, 0, 0, 0);
  }
  int col = n0 + l15;
  float bv = bias ? bias[col] : 0.0f;
  #pragma unroll
  for (int r = 0; r < 4; r++){
    int row = m0 + lhi * 4 + r;
    out[(long)row * ldo + col] = f2bf(acc[r] + bv);
  }
}

// ---------------- fused h = gelu(Bl@Wd^T+bd); Bf^T tile = (h@Wu^T+bu)^T ----------------
// grid (16 row-tiles, 48 col-tiles), 1 wave. h recomputed per col-tile (cheap, parallel).
__global__ __launch_bounds__(64) void k_hb(const unsigned short* __restrict__ Blb,
    const unsigned short* __restrict__ Wdb, const float* __restrict__ bd,
    const unsigned short* __restrict__ Wub, const float* __restrict__ bu,
    unsigned short* __restrict__ Bfmt){
  __shared__ unsigned short hs[16 * 104];
  int l = threadIdx.x, l15 = l & 15, lhi = l >> 4;
  int i = blockIdx.x, n = blockIdx.y;
  f32x4 acc[6];
  #pragma unroll
  for (int d = 0; d < 6; d++) acc[d] = (f32x4)0.0f;
  #pragma unroll
  for (int k0 = 0; k0 < 256; k0 += 32){
    s16x8 a = *(const s16x8*)(Blb + (i * 16 + l15) * 256 + k0 + lhi * 8);
    #pragma unroll
    for (int d = 0; d < 6; d++){
      s16x8 b = *(const s16x8*)(Wdb + (d * 16 + l15) * 256 + k0 + lhi * 8);
      acc[d] = __builtin_amdgcn_mfma_f32_16x16x32_bf16(a, b, acc[d], 0, 0, 0);
    }
  }
  #pragma unroll
  for (int d = 0; d < 6; d++){
    int col = d * 16 + l15;
    float bv = bd[col];
    #pragma unroll
    for (int r = 0; r < 4; r++){
      float v = acc[d][r] + bv;
      v = 0.5f * v * (1.0f + erff(v * 0.70710678118654752f));
      hs[(lhi * 4 + r) * 104 + col] = f2bf(v);
    }
  }
  __syncthreads();
  f32x4 ab = (f32x4)0.0f;
  #pragma unroll
  for (int k0 = 0; k0 < 96; k0 += 32){
    s16x8 a = *(const s16x8*)(hs + l15 * 104 + k0 + lhi * 8);
    s16x8 b = *(const s16x8*)(Wub + (n * 16 + l15) * 96 + k0 + lhi * 8);
    ab = __builtin_amdgcn_mfma_f32_16x16x32_bf16(a, b, ab, 0, 0, 0);
  }
  int col = n * 16 + l15;
  float bv = bu[col];
  #pragma unroll
  for (int r = 0; r < 4; r++)
    Bfmt[(long)col * 256 + i * 16 + lhi * 4 + r] = f2bf(ab[r] + bv);
}

// ---------------- fused t2f = tokens@Wt^T+bt (LDS) ; G' = t2f@Wf^T -> WB[:,768+] ----------------
// grid (7 m-tiles, 6 col-groups), 4 waves. Stage1: 16x768 t2f stripe cooperatively.
__global__ __launch_bounds__(256) void k_tg(const unsigned short* __restrict__ tokensb,
    const unsigned short* __restrict__ Wtb, const float* __restrict__ bt,
    unsigned short* __restrict__ WB){
  __shared__ unsigned short ts[16 * 776];
  int tid = threadIdx.x, w = tid >> 6, l = tid & 63;
  int l15 = l & 15, lhi = l >> 4;
  int m = blockIdx.x, g = blockIdx.y;
  // stage 1: t2f rows m*16..+16; wave w owns n0 = j*4+w, j<12
  f32x4 acc[12];
  #pragma unroll
  for (int j = 0; j < 12; j++) acc[j] = (f32x4)0.0f;
  #pragma unroll 2
  for (int k0 = 0; k0 < 768; k0 += 32){
    s16x8 a = *(const s16x8*)(tokensb + (m * 16 + l15) * 768 + k0 + lhi * 8);
    #pragma unroll
    for (int j = 0; j < 12; j++){
      int n0 = j * 4 + w;
      s16x8 b = *(const s16x8*)(Wtb + (n0 * 16 + l15) * 768 + k0 + lhi * 8);
      acc[j] = __builtin_amdgcn_mfma_f32_16x16x32_bf16(a, b, acc[j], 0, 0, 0);
    }
  }
  #pragma unroll
  for (int j = 0; j < 12; j++){
    int col = (j * 4 + w) * 16 + l15;
    float bv = bt[col];
    #pragma unroll
    for (int r = 0; r < 4; r++)
      ts[(lhi * 4 + r) * 776 + col] = f2bf(acc[j][r] + bv);
  }
  __syncthreads();
  // stage 2: G' tiles n = g*8 + w*2 + {0,1}
  f32x4 a2[2];
  a2[0] = (f32x4)0.0f; a2[1] = (f32x4)0.0f;
  #pragma unroll 2
  for (int k0 = 0; k0 < 768; k0 += 32){
    s16x8 a = *(const s16x8*)(ts + l15 * 776 + k0 + lhi * 8);
    #pragma unroll
    for (int j = 0; j < 2; j++){
      int n = g * 8 + w * 2 + j;
      s16x8 b = *(const s16x8*)(WB + (long)(n * 16 + l15) * 896 + k0 + lhi * 8);
      a2[j] = __builtin_amdgcn_mfma_f32_16x16x32_bf16(a, b, a2[j], 0, 0, 0);
    }
  }
  #pragma unroll
  for (int j = 0; j < 2; j++){
    int n = g * 8 + w * 2 + j;
    int col = n * 16 + l15;
    #pragma unroll
    for (int r = 0; r < 4; r++){
      int row = m * 16 + lhi * 4 + r;
      WB[(long)col * 896 + 768 + row] = (row < 100) ? f2bf(a2[j][r]) : (unsigned short)0;
    }
  }
}

// ---------------- fused cvt + logits + softmax, LDS-staged GEMM form ----------------
__global__ __launch_bounds__(256, 4) void k_attn(const float* __restrict__ xf,
    const unsigned short* __restrict__ tokensb, unsigned short* __restrict__ xb,
    unsigned short* __restrict__ Pbuf){
  __shared__ __align__(16) char smem[40960];
  unsigned short* Xs = (unsigned short*)smem;            // [32][128] us, swizzled
  unsigned short* Ts = (unsigned short*)(smem + 8192);   // [112][128] us, swizzled
  float* st = (float*)smem;                              // post-loop stash overlay

  int tid = threadIdx.x, w = tid >> 6, l = tid & 63;
  int l15 = l & 15, lhi = l >> 4;
  int rg = w >> 1, kh = w & 1;
  long R0 = (long)blockIdx.x * 32;

  f32x4 acc[7];
  #pragma unroll
  for (int nf = 0; nf < 7; nf++) acc[nf] = (f32x4)0.0f;

  int xrow = tid >> 5;           // 0..7 (8 rows per round)
  int xcol = (tid & 31) * 4;     // f32 col within 128-chunk (coalesced)

  for (int it = 0; it < 6; it++){
    #pragma unroll
    for (int i = 0; i < 7; i++){
      int g = (w * 7 + i) * 4 + (l >> 4);          // token row 0..111
      const unsigned short* src = tokensb + (long)g * 768 + it * 128
                                + (((l & 15) * 8) ^ ((g & 7) << 3));
      GLDS16(src, Ts + (w * 7 + i) * 512);
    }
    #pragma unroll
    for (int rnd = 0; rnd < 4; rnd++){
      int row = rnd * 8 + xrow;
      f32x4 v = *(const f32x4*)(xf + (R0 + row) * 768 + it * 128 + xcol);
      u16x4 c;
      #pragma unroll
      for (int j = 0; j < 4; j++) c[j] = f2bf(v[j]);
      *(u16x4*)(xb + (R0 + row) * 768 + it * 128 + xcol) = c;
      *(u16x4*)(Xs + row * 128 + (xcol ^ ((row & 7) << 3))) = c;
    }
    __syncthreads();
    int ar = rg * 16 + l15;
    #pragma unroll
    for (int kk = 0; kk < 2; kk++){
      int coff = kh * 64 + kk * 32 + lhi * 8;
      s16x8 a = *(const s16x8*)(Xs + ar * 128 + (coff ^ ((ar & 7) << 3)));
      #pragma unroll
      for (int nf = 0; nf < 7; nf++){
        int br = nf * 16 + l15;
        s16x8 b = *(const s16x8*)(Ts + br * 128 + (coff ^ ((br & 7) << 3)));
        acc[nf] = __builtin_amdgcn_mfma_f32_16x16x32_bf16(a, b, acc[nf], 0, 0, 0);
      }
    }
    __syncthreads();
  }

  if (kh == 1){
    int widx = rg * 64 + l;
    #pragma unroll
    for (int nf = 0; nf < 7; nf++)
      #pragma unroll
      for (int r = 0; r < 4; r++)
        st[widx * 29 + nf * 4 + r] = acc[nf][r];
  }
  __syncthreads();
  if (kh == 0){
    const float sc = 0.03608439182435161f; // 768^-0.5
    int widx = rg * 64 + l;
    float lg[4][7];
    #pragma unroll
    for (int nf = 0; nf < 7; nf++)
      #pragma unroll
      for (int r = 0; r < 4; r++)
        lg[r][nf] = (acc[nf][r] + st[widx * 29 + nf * 4 + r]) * sc;
    #pragma unroll
    for (int r = 0; r < 4; r++){
      float mx = -1e30f;
      #pragma unroll
      for (int nf = 0; nf < 7; nf++){
        int col = nf * 16 + l15;
        if (col < 100 && lg[r][nf] > mx) mx = lg[r][nf];
      }
      mx = fmaxf(mx, __shfl_xor(mx, 1));
      mx = fmaxf(mx, __shfl_xor(mx, 2));
      mx = fmaxf(mx, __shfl_xor(mx, 4));
      mx = fmaxf(mx, __shfl_xor(mx, 8));
      float p[7], sm = 0.f;
      #pragma unroll
      for (int nf = 0; nf < 7; nf++){
        int col = nf * 16 + l15;
        float v = (col < 100) ? __expf(lg[r][nf] - mx) : 0.f;
        p[nf] = v; sm += v;
      }
      sm += __shfl_xor(sm, 1);
      sm += __shfl_xor(sm, 2);
      sm += __shfl_xor(sm, 4);
      sm += __shfl_xor(sm, 8);
      float inv = 1.f / sm;
      long grow = R0 + rg * 16 + lhi * 4 + r;
      #pragma unroll
      for (int nf = 0; nf < 7; nf++)
        Pbuf[grow * 128 + nf * 16 + l15] = f2bf(p[nf] * inv);
      Pbuf[grow * 128 + 112 + l15] = 0;
    }
  }
}

// ---------------- big GEMM: out = feats + scale*([xb|P] @ WB^T + bf) ----------------
// BM=128 BN=192 BK=64, LDS=80KB -> 2 blocks/CU. 4 waves (2M x 2N), wave tile 64x96.
// Dbuf, counted vmcnt(10), T2 swizzle, T5 setprio. Grid 1024 = 8 XCD x 128.
__global__ __launch_bounds__(256, 2) void k_gemm(const unsigned short* __restrict__ xb,
    const unsigned short* __restrict__ Pbuf, const unsigned short* __restrict__ WB,
    const float* __restrict__ bfv, const float* __restrict__ scalep,
    float* __restrict__ outf){
  extern __shared__ __align__(16) unsigned short lds[];  // A: 2x8192 us; B: 2x12288 us
  unsigned short* ldsB = lds + 16384;
  int bid = blockIdx.x;                 // 1024 = 8 XCD * 128
  int sid = (bid & 7) * 128 + (bid >> 3);
  int mt = sid >> 2, nt = sid & 3;
  long brow = (long)mt * 128;
  int bcol = nt * 192;
  int tid = threadIdx.x, w = tid >> 6, l = tid & 63;
  int l15 = l & 15, lhi = l >> 4;
  int wm = w >> 1, wn = w & 1;          // wave tile: rows wm*64.., cols wn*96..
  int lrow = l >> 3;
  int lsw  = ((l & 7) ^ lrow) * 8;      // pre-swizzled source col (T2 both-sides rule)

  f32x4 acc[4][6];
  #pragma unroll
  for (int m = 0; m < 4; m++)
    #pragma unroll
    for (int n = 0; n < 6; n++) acc[m][n] = (f32x4)0.0f;

  #define STAGE_A(BUF, T) { \
    _Pragma("unroll") \
    for (int ii = 0; ii < 4; ii++){ \
      int r = ii * 32 + w * 8 + lrow; \
      const unsigned short* ga = ((T) < 12) \
        ? xb   + (brow + r) * 768 + (T) * 64 + lsw \
        : Pbuf + (brow + r) * 128 + ((T) - 12) * 64 + lsw; \
      GLDS16(ga, lds + (BUF) * 8192 + (ii * 32 + w * 8) * 64); \
    } }
  #define STAGE_B(BUF, T) { \
    _Pragma("unroll") \
    for (int ii = 0; ii < 6; ii++){ \
      int r = ii * 32 + w * 8 + lrow; \
      const unsigned short* gb = WB + (long)(bcol + r) * 896 + (T) * 64 + lsw; \
      GLDS16(gb, ldsB + (BUF) * 12288 + (ii * 32 + w * 8) * 64); \
    } }

  #define LDA(dst, M, KS) { \
    int ar = wm * 64 + (M) * 16 + l15; \
    int xo = ((KS) * 64 + lhi * 16) ^ ((ar & 7) << 4); \
    dst = *(const s16x8*)(Abuf + ar * 64 + (xo >> 1)); }
  #define LDB(dst, N, KS) { \
    int br = wn * 96 + (N) * 16 + l15; \
    int xo = ((KS) * 64 + lhi * 16) ^ ((br & 7) << 4); \
    dst = *(const s16x8*)(Bbuf + br * 64 + (xo >> 1)); }

  STAGE_A(0, 0);
  STAGE_B(0, 0);

  for (int t = 0; t < 14; t++){
    const unsigned short* Abuf = lds + (t & 1) * 8192;
    const unsigned short* Bbuf = ldsB + (t & 1) * 12288;
    if (t < 13){
      STAGE_A((t + 1) & 1, t + 1);
      STAGE_B((t + 1) & 1, t + 1);
      asm volatile("s_waitcnt vmcnt(10)" ::: "memory");
    } else {
      asm volatile("s_waitcnt vmcnt(0)" ::: "memory");
    }
    __builtin_amdgcn_s_barrier();
    #pragma unroll
    for (int ks = 0; ks < 2; ks++){
      s16x8 bk[6], af[4];
      #pragma unroll
      for (int j = 0; j < 6; j++) LDB(bk[j], j, ks);
      #pragma unroll
      for (int j = 0; j < 4; j++) LDA(af[j], j, ks);
      __builtin_amdgcn_s_setprio(1);
      #pragma unroll
      for (int m = 0; m < 4; m++)
        #pragma unroll
        for (int n = 0; n < 6; n++)
          acc[m][n] = __builtin_amdgcn_mfma_f32_16x16x32_bf16(af[m], bk[n], acc[m][n], 0, 0, 0);
      __builtin_amdgcn_s_setprio(0);
    }
    __builtin_amdgcn_s_barrier();
  }
  #undef STAGE_A
  #undef STAGE_B
  #undef LDA
  #undef LDB

  // ---- epilogue: 2 stash rounds of 64 rows x 192 cols f32 (stride 196), coalesced ----
  __syncthreads();
  float* stf = (float*)lds;      // 64 x 196 x 4 = 50,176 B (dyn LDS = 81,920)
  float scale = *scalep;
  #pragma unroll
  for (int g = 0; g < 2; g++){
    if (wm == g){
      #pragma unroll
      for (int m = 0; m < 4; m++)
        #pragma unroll
        for (int n = 0; n < 6; n++)
          #pragma unroll
          for (int r = 0; r < 4; r++){
            int row = m * 16 + lhi * 4 + r;
            stf[row * 196 + wn * 96 + n * 16 + l15] = acc[m][n][r];
          }
    }
    __syncthreads();
    #pragma unroll
    for (int rp = 0; rp < 12; rp++){
      int idx = rp * 256 + tid;
      int row = idx / 48, c4 = idx - row * 48;
      int col = c4 * 4;
      long grow = brow + g * 64 + row;
      int gcol = bcol + col;
      f32x4 v = *(const f32x4*)(stf + row * 196 + col);
      f32x4 bias = *(const f32x4*)(bfv + gcol);
      u16x4 fb = *(const u16x4*)(xb + grow * 768 + gcol);
      f32x4 o;
      #pragma unroll
      for (int j = 0; j < 4; j++) o[j] = bf2f(fb[j]) + scale * (v[j] + bias[j]);
      *(f32x4*)(outf + grow * 768 + gcol) = o;
    }
    __syncthreads();
  }
}

extern "C" void kernel_launch(void* const* d_in, const int* in_sizes, int n_in,
                              void* d_out, int out_size, void* d_ws, size_t ws_size,
                              hipStream_t stream) {
  const float* x   = (const float*)d_in[0];
  const float* Wd  = (const float*)d_in[1];
  const float* bd  = (const float*)d_in[2];
  const float* Wu  = (const float*)d_in[3];
  const float* bu  = (const float*)d_in[4];
  const float* Wt  = (const float*)d_in[5];
  const float* bt  = (const float*)d_in[6];
  const float* Wf  = (const float*)d_in[7];
  const float* bfv = (const float*)d_in[8];
  const float* Ap  = (const float*)d_in[9];
  const float* Bp  = (const float*)d_in[10];
  const float* scalep = (const float*)d_in[11];
  const int* layerp   = (const int*)d_in[12];
  float* out = (float*)d_out;

  char* ws = (char*)d_ws;
  unsigned short* xb      = (unsigned short*)(ws);              // 50,331,648
  unsigned short* Pbuf    = (unsigned short*)(ws + 50331648);   //  8,388,608
  unsigned short* WB      = (unsigned short*)(ws + 58720256);   //  1,376,256 (768 x 896)
  unsigned short* Wtb     = (unsigned short*)(ws + 60096512);   //  1,179,648 (768 x 768)
  unsigned short* tokensb = (unsigned short*)(ws + 61276160);   //    172,032 (112 x 768)
  unsigned short* Ab      = (unsigned short*)(ws + 61620224);   //     57,344 (112 x 256)
  unsigned short* Blb     = (unsigned short*)(ws + 61677568);   //    131,072 (256 x 256)
  unsigned short* Wdb     = (unsigned short*)(ws + 61808640);   //     49,152 ( 96 x 256)
  unsigned short* Wub     = (unsigned short*)(ws + 61857792);   //    147,456 (768 x  96)
  unsigned short* Bfmt    = (unsigned short*)(ws + 62054400);   //    393,216 (768 x 256, Bf^T)

  const float* xf = x + 32 * 768;   // feats (skip cls rows)
  float* outf = out + 32 * 768;

  static int lds_attr_set = 0;
  if (!lds_attr_set){
    hipFuncSetAttribute((const void*)k_gemm, hipFuncAttributeMaxDynamicSharedMemorySize, 81920);
    lds_attr_set = 1;
  }

  k_prep<<<dim3(2688, 7), 256, 0, stream>>>(Wd, Wu, Wt, Wf, Ap, Bp, layerp, x, out,
                                            Wdb, Wub, Wtb, WB, Ab, Blb);
  k_hb<<<dim3(16, 48), 64, 0, stream>>>(Blb, Wdb, bd, Wub, bu, Bfmt);
  k_mm<2><<<dim3(7, 48), 64, 0, stream>>>(Ab, 256, Bfmt, 256, 256, nullptr, tokensb, 768);
  k_tg<<<dim3(7, 6), 256, 0, stream>>>(tokensb, Wtb, bt, WB);
  k_attn<<<1024, 256, 0, stream>>>(xf, tokensb, xb, Pbuf);
  k_gemm<<<1024, 256, 81920, stream>>>(xb, Pbuf, WB, bfv, scalep, outf);
}

// Round 13
// 126.954 us; speedup vs baseline: 1.2582x; 1.2582x over previous
//
#include <hip/hip_runtime.h>
#include <hip/hip_bf16.h>
#include <cmath>

using f32x4 = __attribute__((ext_vector_type(4))) float;
using s16x8 = __attribute__((ext_vector_type(8))) short;
using u16x4 = __attribute__((ext_vector_type(4))) unsigned short;

__device__ __forceinline__ float bf2f(unsigned short u){
  union { unsigned int i; float f; } v; v.i = ((unsigned int)u) << 16; return v.f;
}
__device__ __forceinline__ unsigned short f2bf(float f){
  union { float f; unsigned int i; } v; v.f = f;
  return (unsigned short)((v.i + 0x7FFFu + ((v.i >> 16) & 1u)) >> 16);
}

#define GLDS16(g, l) __builtin_amdgcn_global_load_lds( \
    (const __attribute__((address_space(1))) unsigned int*)(g), \
    (__attribute__((address_space(3))) unsigned int*)(l), 16, 0, 0)

// ---------------- prep: bf16 conversions + cls passthrough ----------------
__global__ void k_prep(const float* __restrict__ Wd, const float* __restrict__ Wu,
                       const float* __restrict__ Wt, const float* __restrict__ Wf,
                       const float* __restrict__ Ap, const float* __restrict__ Bp,
                       const int* __restrict__ layerp, const float* __restrict__ x,
                       float* __restrict__ out,
                       unsigned short* __restrict__ Wdb, unsigned short* __restrict__ Wub,
                       unsigned short* __restrict__ Wtb, unsigned short* __restrict__ WB,
                       unsigned short* __restrict__ Ab, unsigned short* __restrict__ Blb){
  int idx = blockIdx.x * 256 + threadIdx.x;
  switch (blockIdx.y){
    case 0: if (idx < 24576)  Wdb[idx] = f2bf(Wd[idx]); break;
    case 1: if (idx < 73728)  Wub[idx] = f2bf(Wu[idx]); break;
    case 2: if (idx < 589824) Wtb[idx] = f2bf(Wt[idx]); break;
    case 3: if (idx < 688128){
      int n = idx / 896, c = idx - n * 896;
      WB[idx] = (c < 768) ? f2bf(Wf[n * 768 + c]) : (unsigned short)0;
    } break;
    case 4: if (idx < 28672){
      int r = idx >> 8;
      Ab[idx] = (r < 100) ? f2bf(Ap[idx]) : (unsigned short)0;
    } break;
    case 5: if (idx < 65536) Blb[idx] = f2bf(Bp[(long)(*layerp) * 65536 + idx]); break;
    case 6: if (idx < 24576) out[idx] = x[idx]; break;   // cls passthrough
  }
}

// ---------------- 2-wave split-K MFMA mini-GEMM: out = epi(A @ B^T + bias) ----------------
// Wave w takes k-steps s where s%2==w; LDS combine; wave 0 does epilogue.
// EPI 0: gelu row-major   EPI 1: transposed store   EPI 2: row-major   EPI 3: WB col 768+
template<int EPI>
__global__ __launch_bounds__(128) void k_mm(const unsigned short* __restrict__ A, int lda,
    const unsigned short* __restrict__ B, int ldb, int K,
    const float* __restrict__ bias, unsigned short* __restrict__ out, int ldo){
  __shared__ float lacc[16 * 17];
  int tid = threadIdx.x, w = tid >> 6, l = tid & 63;
  int l15 = l & 15, lhi = l >> 4;
  int m0 = blockIdx.x * 16, n0 = blockIdx.y * 16;
  f32x4 acc = (f32x4)0.0f;
  int nsteps = K >> 5;
  for (int s = w; s < nsteps; s += 2){
    int k0 = s * 32;
    s16x8 a = *(const s16x8*)(A + (long)(m0 + l15) * lda + k0 + lhi * 8);
    s16x8 b = *(const s16x8*)(B + (long)(n0 + l15) * ldb + k0 + lhi * 8);
    acc = __builtin_amdgcn_mfma_f32_16x16x32_bf16(a, b, acc, 0, 0, 0);
  }
  if (w == 1){
    #pragma unroll
    for (int r = 0; r < 4; r++) lacc[(lhi * 4 + r) * 17 + l15] = acc[r];
  }
  __syncthreads();
  if (w == 0){
    int col = n0 + l15;
    float bv = bias ? bias[col] : 0.0f;
    #pragma unroll
    for (int r = 0; r < 4; r++){
      int row = m0 + lhi * 4 + r;
      float v = acc[r] + lacc[(lhi * 4 + r) * 17 + l15] + bv;
      if (EPI == 0){
        v = 0.5f * v * (1.0f + erff(v * 0.70710678118654752f));
        out[(long)row * ldo + col] = f2bf(v);
      } else if (EPI == 1){
        out[(long)col * ldo + row] = f2bf(v);
      } else if (EPI == 2){
        out[(long)row * ldo + col] = f2bf(v);
      } else {
        out[(long)col * 896 + 768 + row] = (row < 100) ? f2bf(v) : (unsigned short)0;
      }
    }
  }
}

// ---------------- fused cvt + logits + softmax, LDS-staged GEMM form ----------------
__global__ __launch_bounds__(256, 4) void k_attn(const float* __restrict__ xf,
    const unsigned short* __restrict__ tokensb, unsigned short* __restrict__ xb,
    unsigned short* __restrict__ Pbuf){
  __shared__ __align__(16) char smem[40960];
  unsigned short* Xs = (unsigned short*)smem;            // [32][128] us, swizzled
  unsigned short* Ts = (unsigned short*)(smem + 8192);   // [112][128] us, swizzled
  float* st = (float*)smem;                              // post-loop stash overlay

  int tid = threadIdx.x, w = tid >> 6, l = tid & 63;
  int l15 = l & 15, lhi = l >> 4;
  int rg = w >> 1, kh = w & 1;
  long R0 = (long)blockIdx.x * 32;

  f32x4 acc[7];
  #pragma unroll
  for (int nf = 0; nf < 7; nf++) acc[nf] = (f32x4)0.0f;

  int xrow = tid >> 5;           // 0..7 (8 rows per round)
  int xcol = (tid & 31) * 4;     // f32 col within 128-chunk (coalesced)

  for (int it = 0; it < 6; it++){
    #pragma unroll
    for (int i = 0; i < 7; i++){
      int g = (w * 7 + i) * 4 + (l >> 4);          // token row 0..111
      const unsigned short* src = tokensb + (long)g * 768 + it * 128
                                + (((l & 15) * 8) ^ ((g & 7) << 3));
      GLDS16(src, Ts + (w * 7 + i) * 512);
    }
    #pragma unroll
    for (int rnd = 0; rnd < 4; rnd++){
      int row = rnd * 8 + xrow;
      f32x4 v = *(const f32x4*)(xf + (R0 + row) * 768 + it * 128 + xcol);
      u16x4 c;
      #pragma unroll
      for (int j = 0; j < 4; j++) c[j] = f2bf(v[j]);
      *(u16x4*)(xb + (R0 + row) * 768 + it * 128 + xcol) = c;
      *(u16x4*)(Xs + row * 128 + (xcol ^ ((row & 7) << 3))) = c;
    }
    __syncthreads();
    int ar = rg * 16 + l15;
    #pragma unroll
    for (int kk = 0; kk < 2; kk++){
      int coff = kh * 64 + kk * 32 + lhi * 8;
      s16x8 a = *(const s16x8*)(Xs + ar * 128 + (coff ^ ((ar & 7) << 3)));
      #pragma unroll
      for (int nf = 0; nf < 7; nf++){
        int br = nf * 16 + l15;
        s16x8 b = *(const s16x8*)(Ts + br * 128 + (coff ^ ((br & 7) << 3)));
        acc[nf] = __builtin_amdgcn_mfma_f32_16x16x32_bf16(a, b, acc[nf], 0, 0, 0);
      }
    }
    __syncthreads();
  }

  if (kh == 1){
    int widx = rg * 64 + l;
    #pragma unroll
    for (int nf = 0; nf < 7; nf++)
      #pragma unroll
      for (int r = 0; r < 4; r++)
        st[widx * 29 + nf * 4 + r] = acc[nf][r];
  }
  __syncthreads();
  if (kh == 0){
    const float sc = 0.03608439182435161f; // 768^-0.5
    int widx = rg * 64 + l;
    float lg[4][7];
    #pragma unroll
    for (int nf = 0; nf < 7; nf++)
      #pragma unroll
      for (int r = 0; r < 4; r++)
        lg[r][nf] = (acc[nf][r] + st[widx * 29 + nf * 4 + r]) * sc;
    #pragma unroll
    for (int r = 0; r < 4; r++){
      float mx = -1e30f;
      #pragma unroll
      for (int nf = 0; nf < 7; nf++){
        int col = nf * 16 + l15;
        if (col < 100 && lg[r][nf] > mx) mx = lg[r][nf];
      }
      mx = fmaxf(mx, __shfl_xor(mx, 1));
      mx = fmaxf(mx, __shfl_xor(mx, 2));
      mx = fmaxf(mx, __shfl_xor(mx, 4));
      mx = fmaxf(mx, __shfl_xor(mx, 8));
      float p[7], sm = 0.f;
      #pragma unroll
      for (int nf = 0; nf < 7; nf++){
        int col = nf * 16 + l15;
        float v = (col < 100) ? __expf(lg[r][nf] - mx) : 0.f;
        p[nf] = v; sm += v;
      }
      sm += __shfl_xor(sm, 1);
      sm += __shfl_xor(sm, 2);
      sm += __shfl_xor(sm, 4);
      sm += __shfl_xor(sm, 8);
      float inv = 1.f / sm;
      long grow = R0 + rg * 16 + lhi * 4 + r;
      #pragma unroll
      for (int nf = 0; nf < 7; nf++)
        Pbuf[grow * 128 + nf * 16 + l15] = f2bf(p[nf] * inv);
      Pbuf[grow * 128 + 112 + l15] = 0;
    }
  }
}

// ---------------- big GEMM: out = feats + scale*([xb|P] @ WB^T + bf) ----------------
// BM=128 BN=192 BK=64, LDS=80KB -> 2 blocks/CU. 4 waves (2M x 2N), wave tile 64x96.
// Dbuf, counted vmcnt(10), T2 swizzle, T5 setprio. Grid 1024 = 8 XCD x 128.
__global__ __launch_bounds__(256, 2) void k_gemm(const unsigned short* __restrict__ xb,
    const unsigned short* __restrict__ Pbuf, const unsigned short* __restrict__ WB,
    const float* __restrict__ bfv, const float* __restrict__ scalep,
    float* __restrict__ outf){
  extern __shared__ __align__(16) unsigned short lds[];  // A: 2x8192 us; B: 2x12288 us
  unsigned short* ldsB = lds + 16384;
  int bid = blockIdx.x;                 // 1024 = 8 XCD * 128
  int sid = (bid & 7) * 128 + (bid >> 3);
  int mt = sid >> 2, nt = sid & 3;
  long brow = (long)mt * 128;
  int bcol = nt * 192;
  int tid = threadIdx.x, w = tid >> 6, l = tid & 63;
  int l15 = l & 15, lhi = l >> 4;
  int wm = w >> 1, wn = w & 1;          // wave tile: rows wm*64.., cols wn*96..
  int lrow = l >> 3;
  int lsw  = ((l & 7) ^ lrow) * 8;      // pre-swizzled source col (T2 both-sides rule)

  f32x4 acc[4][6];
  #pragma unroll
  for (int m = 0; m < 4; m++)
    #pragma unroll
    for (int n = 0; n < 6; n++) acc[m][n] = (f32x4)0.0f;

  #define STAGE_A(BUF, T) { \
    _Pragma("unroll") \
    for (int ii = 0; ii < 4; ii++){ \
      int r = ii * 32 + w * 8 + lrow; \
      const unsigned short* ga = ((T) < 12) \
        ? xb   + (brow + r) * 768 + (T) * 64 + lsw \
        : Pbuf + (brow + r) * 128 + ((T) - 12) * 64 + lsw; \
      GLDS16(ga, lds + (BUF) * 8192 + (ii * 32 + w * 8) * 64); \
    } }
  #define STAGE_B(BUF, T) { \
    _Pragma("unroll") \
    for (int ii = 0; ii < 6; ii++){ \
      int r = ii * 32 + w * 8 + lrow; \
      const unsigned short* gb = WB + (long)(bcol + r) * 896 + (T) * 64 + lsw; \
      GLDS16(gb, ldsB + (BUF) * 12288 + (ii * 32 + w * 8) * 64); \
    } }

  #define LDA(dst, M, KS) { \
    int ar = wm * 64 + (M) * 16 + l15; \
    int xo = ((KS) * 64 + lhi * 16) ^ ((ar & 7) << 4); \
    dst = *(const s16x8*)(Abuf + ar * 64 + (xo >> 1)); }
  #define LDB(dst, N, KS) { \
    int br = wn * 96 + (N) * 16 + l15; \
    int xo = ((KS) * 64 + lhi * 16) ^ ((br & 7) << 4); \
    dst = *(const s16x8*)(Bbuf + br * 64 + (xo >> 1)); }

  STAGE_A(0, 0);
  STAGE_B(0, 0);

  for (int t = 0; t < 14; t++){
    const unsigned short* Abuf = lds + (t & 1) * 8192;
    const unsigned short* Bbuf = ldsB + (t & 1) * 12288;
    if (t < 13){
      STAGE_A((t + 1) & 1, t + 1);
      STAGE_B((t + 1) & 1, t + 1);
      asm volatile("s_waitcnt vmcnt(10)" ::: "memory");
    } else {
      asm volatile("s_waitcnt vmcnt(0)" ::: "memory");
    }
    __builtin_amdgcn_s_barrier();
    #pragma unroll
    for (int ks = 0; ks < 2; ks++){
      s16x8 bk[6], af[4];
      #pragma unroll
      for (int j = 0; j < 6; j++) LDB(bk[j], j, ks);
      #pragma unroll
      for (int j = 0; j < 4; j++) LDA(af[j], j, ks);
      __builtin_amdgcn_s_setprio(1);
      #pragma unroll
      for (int m = 0; m < 4; m++)
        #pragma unroll
        for (int n = 0; n < 6; n++)
          acc[m][n] = __builtin_amdgcn_mfma_f32_16x16x32_bf16(af[m], bk[n], acc[m][n], 0, 0, 0);
      __builtin_amdgcn_s_setprio(0);
    }
    __builtin_amdgcn_s_barrier();
  }
  #undef STAGE_A
  #undef STAGE_B
  #undef LDA
  #undef LDB

  // ---- epilogue: 2 stash rounds of 64 rows x 192 cols f32 (stride 196), coalesced ----
  __syncthreads();
  float* stf = (float*)lds;      // 64 x 196 x 4 = 50,176 B (dyn LDS = 81,920)
  float scale = *scalep;
  #pragma unroll
  for (int g = 0; g < 2; g++){
    if (wm == g){
      #pragma unroll
      for (int m = 0; m < 4; m++)
        #pragma unroll
        for (int n = 0; n < 6; n++)
          #pragma unroll
          for (int r = 0; r < 4; r++){
            int row = m * 16 + lhi * 4 + r;
            stf[row * 196 + wn * 96 + n * 16 + l15] = acc[m][n][r];
          }
    }
    __syncthreads();
    #pragma unroll
    for (int rp = 0; rp < 12; rp++){
      int idx = rp * 256 + tid;
      int row = idx / 48, c4 = idx - row * 48;
      int col = c4 * 4;
      long grow = brow + g * 64 + row;
      int gcol = bcol + col;
      f32x4 v = *(const f32x4*)(stf + row * 196 + col);
      f32x4 bias = *(const f32x4*)(bfv + gcol);
      u16x4 fb = *(const u16x4*)(xb + grow * 768 + gcol);
      f32x4 o;
      #pragma unroll
      for (int j = 0; j < 4; j++) o[j] = bf2f(fb[j]) + scale * (v[j] + bias[j]);
      *(f32x4*)(outf + grow * 768 + gcol) = o;
    }
    __syncthreads();
  }
}

extern "C" void kernel_launch(void* const* d_in, const int* in_sizes, int n_in,
                              void* d_out, int out_size, void* d_ws, size_t ws_size,
                              hipStream_t stream) {
  const float* x   = (const float*)d_in[0];
  const float* Wd  = (const float*)d_in[1];
  const float* bd  = (const float*)d_in[2];
  const float* Wu  = (const float*)d_in[3];
  const float* bu  = (const float*)d_in[4];
  const float* Wt  = (const float*)d_in[5];
  const float* bt  = (const float*)d_in[6];
  const float* Wf  = (const float*)d_in[7];
  const float* bfv = (const float*)d_in[8];
  const float* Ap  = (const float*)d_in[9];
  const float* Bp  = (const float*)d_in[10];
  const float* scalep = (const float*)d_in[11];
  const int* layerp   = (const int*)d_in[12];
  float* out = (float*)d_out;

  char* ws = (char*)d_ws;
  unsigned short* xb      = (unsigned short*)(ws);              // 50,331,648
  unsigned short* Pbuf    = (unsigned short*)(ws + 50331648);   //  8,388,608
  unsigned short* WB      = (unsigned short*)(ws + 58720256);   //  1,376,256 (768 x 896)
  unsigned short* Wtb     = (unsigned short*)(ws + 60096512);   //  1,179,648 (768 x 768)
  unsigned short* tokensb = (unsigned short*)(ws + 61276160);   //    172,032 (112 x 768)
  unsigned short* t2fb    = (unsigned short*)(ws + 61448192);   //    172,032 (112 x 768)
  unsigned short* Ab      = (unsigned short*)(ws + 61620224);   //     57,344 (112 x 256)
  unsigned short* Blb     = (unsigned short*)(ws + 61677568);   //    131,072 (256 x 256)
  unsigned short* Wdb     = (unsigned short*)(ws + 61808640);   //     49,152 ( 96 x 256)
  unsigned short* Wub     = (unsigned short*)(ws + 61857792);   //    147,456 (768 x  96)
  unsigned short* hb      = (unsigned short*)(ws + 62005248);   //     49,152 (256 x  96)
  unsigned short* Bfmt    = (unsigned short*)(ws + 62054400);   //    393,216 (768 x 256, Bf^T)

  const float* xf = x + 32 * 768;   // feats (skip cls rows)
  float* outf = out + 32 * 768;

  static int lds_attr_set = 0;
  if (!lds_attr_set){
    hipFuncSetAttribute((const void*)k_gemm, hipFuncAttributeMaxDynamicSharedMemorySize, 81920);
    lds_attr_set = 1;
  }

  k_prep<<<dim3(2688, 7), 256, 0, stream>>>(Wd, Wu, Wt, Wf, Ap, Bp, layerp, x, out,
                                            Wdb, Wub, Wtb, WB, Ab, Blb);
  k_mm<0><<<dim3(16, 6),  128, 0, stream>>>(Blb, 256, Wdb, 256, 256, bd, hb, 96);
  k_mm<1><<<dim3(16, 48), 128, 0, stream>>>(hb, 96, Wub, 96, 96, bu, Bfmt, 256);
  k_mm<2><<<dim3(7, 48),  128, 0, stream>>>(Ab, 256, Bfmt, 256, 256, nullptr, tokensb, 768);
  k_mm<2><<<dim3(7, 48),  128, 0, stream>>>(tokensb, 768, Wtb, 768, 768, bt, t2fb, 768);
  k_mm<3><<<dim3(7, 48),  128, 0, stream>>>(t2fb, 768, WB, 896, 768, nullptr, WB, 0);

  k_attn<<<1024, 256, 0, stream>>>(xf, tokensb, xb, Pbuf);
  k_gemm<<<1024, 256, 81920, stream>>>(xb, Pbuf, WB, bfv, scalep, outf);
}

// Round 14
// 122.927 us; speedup vs baseline: 1.2994x; 1.0328x over previous
//
#include <hip/hip_runtime.h>
#include <hip/hip_bf16.h>
#include <cmath>

using f32x4 = __attribute__((ext_vector_type(4))) float;
using s16x8 = __attribute__((ext_vector_type(8))) short;
using u16x4 = __attribute__((ext_vector_type(4))) unsigned short;

__device__ __forceinline__ float bf2f(unsigned short u){
  union { unsigned int i; float f; } v; v.i = ((unsigned int)u) << 16; return v.f;
}
__device__ __forceinline__ unsigned short f2bf(float f){
  union { float f; unsigned int i; } v; v.f = f;
  return (unsigned short)((v.i + 0x7FFFu + ((v.i >> 16) & 1u)) >> 16);
}

#define GLDS16(g, l) __builtin_amdgcn_global_load_lds( \
    (const __attribute__((address_space(1))) unsigned int*)(g), \
    (__attribute__((address_space(3))) unsigned int*)(l), 16, 0, 0)

// ---------------- prep: bf16 conversions + cls passthrough ----------------
__global__ void k_prep(const float* __restrict__ Wd, const float* __restrict__ Wu,
                       const float* __restrict__ Wt, const float* __restrict__ Wf,
                       const float* __restrict__ Ap, const float* __restrict__ Bp,
                       const int* __restrict__ layerp, const float* __restrict__ x,
                       float* __restrict__ out,
                       unsigned short* __restrict__ Wdb, unsigned short* __restrict__ Wub,
                       unsigned short* __restrict__ Wtb, unsigned short* __restrict__ WB,
                       unsigned short* __restrict__ Ab, unsigned short* __restrict__ Blb){
  int idx = blockIdx.x * 256 + threadIdx.x;
  switch (blockIdx.y){
    case 0: if (idx < 24576)  Wdb[idx] = f2bf(Wd[idx]); break;
    case 1: if (idx < 73728)  Wub[idx] = f2bf(Wu[idx]); break;
    case 2: if (idx < 589824) Wtb[idx] = f2bf(Wt[idx]); break;
    case 3: if (idx < 688128){
      int n = idx / 896, c = idx - n * 896;
      WB[idx] = (c < 768) ? f2bf(Wf[n * 768 + c]) : (unsigned short)0;
    } break;
    case 4: if (idx < 28672){
      int r = idx >> 8;
      Ab[idx] = (r < 100) ? f2bf(Ap[idx]) : (unsigned short)0;
    } break;
    case 5: if (idx < 65536) Blb[idx] = f2bf(Bp[(long)(*layerp) * 65536 + idx]); break;
    case 6: if (idx < 24576) out[idx] = x[idx]; break;   // cls passthrough
  }
}

// ---------------- 2-wave split-K MFMA mini-GEMM: out = epi(A @ B^T + bias) ----------------
template<int EPI>
__global__ __launch_bounds__(128) void k_mm(const unsigned short* __restrict__ A, int lda,
    const unsigned short* __restrict__ B, int ldb, int K,
    const float* __restrict__ bias, unsigned short* __restrict__ out, int ldo){
  __shared__ float lacc[16 * 17];
  int tid = threadIdx.x, w = tid >> 6, l = tid & 63;
  int l15 = l & 15, lhi = l >> 4;
  int m0 = blockIdx.x * 16, n0 = blockIdx.y * 16;
  f32x4 acc = (f32x4)0.0f;
  int nsteps = K >> 5;
  for (int s = w; s < nsteps; s += 2){
    int k0 = s * 32;
    s16x8 a = *(const s16x8*)(A + (long)(m0 + l15) * lda + k0 + lhi * 8);
    s16x8 b = *(const s16x8*)(B + (long)(n0 + l15) * ldb + k0 + lhi * 8);
    acc = __builtin_amdgcn_mfma_f32_16x16x32_bf16(a, b, acc, 0, 0, 0);
  }
  if (w == 1){
    #pragma unroll
    for (int r = 0; r < 4; r++) lacc[(lhi * 4 + r) * 17 + l15] = acc[r];
  }
  __syncthreads();
  if (w == 0){
    int col = n0 + l15;
    float bv = bias ? bias[col] : 0.0f;
    #pragma unroll
    for (int r = 0; r < 4; r++){
      int row = m0 + lhi * 4 + r;
      float v = acc[r] + lacc[(lhi * 4 + r) * 17 + l15] + bv;
      if (EPI == 0){
        v = 0.5f * v * (1.0f + erff(v * 0.70710678118654752f));
        out[(long)row * ldo + col] = f2bf(v);
      } else if (EPI == 1){
        out[(long)col * ldo + row] = f2bf(v);
      } else if (EPI == 2){
        out[(long)row * ldo + col] = f2bf(v);
      } else {
        out[(long)col * 896 + 768 + row] = (row < 100) ? f2bf(v) : (unsigned short)0;
      }
    }
  }
}

// ---------------- fused cvt + logits + softmax (no xb write) ----------------
__global__ __launch_bounds__(256, 4) void k_attn(const float* __restrict__ xf,
    const unsigned short* __restrict__ tokensb, unsigned short* __restrict__ Pbuf){
  __shared__ __align__(16) char smem[40960];
  unsigned short* Xs = (unsigned short*)smem;            // [32][128] us, swizzled
  unsigned short* Ts = (unsigned short*)(smem + 8192);   // [112][128] us, swizzled
  float* st = (float*)smem;                              // post-loop stash overlay

  int tid = threadIdx.x, w = tid >> 6, l = tid & 63;
  int l15 = l & 15, lhi = l >> 4;
  int rg = w >> 1, kh = w & 1;
  long R0 = (long)blockIdx.x * 32;

  f32x4 acc[7];
  #pragma unroll
  for (int nf = 0; nf < 7; nf++) acc[nf] = (f32x4)0.0f;

  int xrow = tid >> 5;           // 0..7 (8 rows per round)
  int xcol = (tid & 31) * 4;     // f32 col within 128-chunk (coalesced)

  for (int it = 0; it < 6; it++){
    #pragma unroll
    for (int i = 0; i < 7; i++){
      int g = (w * 7 + i) * 4 + (l >> 4);          // token row 0..111
      const unsigned short* src = tokensb + (long)g * 768 + it * 128
                                + (((l & 15) * 8) ^ ((g & 7) << 3));
      GLDS16(src, Ts + (w * 7 + i) * 512);
    }
    #pragma unroll
    for (int rnd = 0; rnd < 4; rnd++){
      int row = rnd * 8 + xrow;
      f32x4 v = *(const f32x4*)(xf + (R0 + row) * 768 + it * 128 + xcol);
      u16x4 c;
      #pragma unroll
      for (int j = 0; j < 4; j++) c[j] = f2bf(v[j]);
      *(u16x4*)(Xs + row * 128 + (xcol ^ ((row & 7) << 3))) = c;
    }
    __syncthreads();
    int ar = rg * 16 + l15;
    #pragma unroll
    for (int kk = 0; kk < 2; kk++){
      int coff = kh * 64 + kk * 32 + lhi * 8;
      s16x8 a = *(const s16x8*)(Xs + ar * 128 + (coff ^ ((ar & 7) << 3)));
      #pragma unroll
      for (int nf = 0; nf < 7; nf++){
        int br = nf * 16 + l15;
        s16x8 b = *(const s16x8*)(Ts + br * 128 + (coff ^ ((br & 7) << 3)));
        acc[nf] = __builtin_amdgcn_mfma_f32_16x16x32_bf16(a, b, acc[nf], 0, 0, 0);
      }
    }
    __syncthreads();
  }

  if (kh == 1){
    int widx = rg * 64 + l;
    #pragma unroll
    for (int nf = 0; nf < 7; nf++)
      #pragma unroll
      for (int r = 0; r < 4; r++)
        st[widx * 29 + nf * 4 + r] = acc[nf][r];
  }
  __syncthreads();
  if (kh == 0){
    const float sc = 0.03608439182435161f; // 768^-0.5
    int widx = rg * 64 + l;
    float lg[4][7];
    #pragma unroll
    for (int nf = 0; nf < 7; nf++)
      #pragma unroll
      for (int r = 0; r < 4; r++)
        lg[r][nf] = (acc[nf][r] + st[widx * 29 + nf * 4 + r]) * sc;
    #pragma unroll
    for (int r = 0; r < 4; r++){
      float mx = -1e30f;
      #pragma unroll
      for (int nf = 0; nf < 7; nf++){
        int col = nf * 16 + l15;
        if (col < 100 && lg[r][nf] > mx) mx = lg[r][nf];
      }
      mx = fmaxf(mx, __shfl_xor(mx, 1));
      mx = fmaxf(mx, __shfl_xor(mx, 2));
      mx = fmaxf(mx, __shfl_xor(mx, 4));
      mx = fmaxf(mx, __shfl_xor(mx, 8));
      float p[7], sm = 0.f;
      #pragma unroll
      for (int nf = 0; nf < 7; nf++){
        int col = nf * 16 + l15;
        float v = (col < 100) ? __expf(lg[r][nf] - mx) : 0.f;
        p[nf] = v; sm += v;
      }
      sm += __shfl_xor(sm, 1);
      sm += __shfl_xor(sm, 2);
      sm += __shfl_xor(sm, 4);
      sm += __shfl_xor(sm, 8);
      float inv = 1.f / sm;
      long grow = R0 + rg * 16 + lhi * 4 + r;
      #pragma unroll
      for (int nf = 0; nf < 7; nf++)
        Pbuf[grow * 128 + nf * 16 + l15] = f2bf(p[nf] * inv);
      Pbuf[grow * 128 + 112 + l15] = 0;
    }
  }
}

// ---------------- big GEMM: out = xf + scale*([bf16(xf)|P] @ WB^T + bf) ----------------
// BM=128 BN=192 BK=64, LDS=56KB -> 2 blocks/CU. A from xf (L3) via reg-staged cvt
// (t<12) or Pbuf gl_lds (t>=12). One barrier/iter, exact-FIFO counted vmcnt.
__global__ __launch_bounds__(256, 2) void k_gemm(const float* __restrict__ xf,
    const unsigned short* __restrict__ Pbuf, const unsigned short* __restrict__ WB,
    const float* __restrict__ bfv, const float* __restrict__ scalep,
    float* __restrict__ outf){
  extern __shared__ __align__(16) unsigned short lds[];  // A: 2x8192 us; B: 2x12288 us
  unsigned short* ldsB = lds + 16384;
  int bid = blockIdx.x;                 // 1024 = 8 XCD * 128
  int sid = (bid & 7) * 128 + (bid >> 3);
  int mt = sid >> 2, nt = sid & 3;
  long brow = (long)mt * 128;
  int bcol = nt * 192;
  int tid = threadIdx.x, w = tid >> 6, l = tid & 63;
  int l15 = l & 15, lhi = l >> 4;
  int wm = w >> 1, wn = w & 1;          // wave tile: rows wm*64.., cols wn*96..
  int lrow = l >> 3;                    // 0..7
  int lc   = l & 7;                     // 16B col slot
  int lsw  = (lc ^ lrow) * 8;           // swizzled col (ushorts)

  f32x4 acc[4][6];
  #pragma unroll
  for (int m = 0; m < 4; m++)
    #pragma unroll
    for (int n = 0; n < 6; n++) acc[m][n] = (f32x4)0.0f;

  f32x4 av0[4], av1[4];   // in-flight A f32 values

  // issue coalesced f32 loads of A-tile T (rows ii*32+w*8+lrow, cols T*64+lc*8)
  #define AISSUE(T) { \
    _Pragma("unroll") \
    for (int ii = 0; ii < 4; ii++){ \
      int r = ii * 32 + w * 8 + lrow; \
      const float* gs = xf + (brow + r) * 768 + (T) * 64 + lc * 8; \
      av0[ii] = *(const f32x4*)gs; av1[ii] = *(const f32x4*)(gs + 4); \
    } }
  // cvt + swizzled ds_write (r&7 == lrow, so swizzle == lsw)
  #define AWRITE(BUF) { \
    _Pragma("unroll") \
    for (int ii = 0; ii < 4; ii++){ \
      int r = ii * 32 + w * 8 + lrow; \
      s16x8 c; \
      _Pragma("unroll") \
      for (int j = 0; j < 4; j++){ c[j] = (short)f2bf(av0[ii][j]); c[4+j] = (short)f2bf(av1[ii][j]); } \
      *(s16x8*)(lds + (BUF) * 8192 + r * 64 + lsw) = c; \
    } }
  // P-tiles via gl_lds (linear dest, pre-swizzled source)
  #define APBUF(BUF, T) { \
    _Pragma("unroll") \
    for (int ii = 0; ii < 4; ii++){ \
      int r = ii * 32 + w * 8 + lrow; \
      const unsigned short* ga = Pbuf + (brow + r) * 128 + ((T) - 12) * 64 + lsw; \
      GLDS16(ga, lds + (BUF) * 8192 + (ii * 32 + w * 8) * 64); \
    } }
  #define STAGE_B(BUF, T) { \
    _Pragma("unroll") \
    for (int ii = 0; ii < 6; ii++){ \
      int r = ii * 32 + w * 8 + lrow; \
      const unsigned short* gb = WB + (long)(bcol + r) * 896 + (T) * 64 + lsw; \
      GLDS16(gb, ldsB + (BUF) * 12288 + (ii * 32 + w * 8) * 64); \
    } }

  #define LDA(dst, M, KS) { \
    int ar = wm * 64 + (M) * 16 + l15; \
    int xo = ((KS) * 64 + lhi * 16) ^ ((ar & 7) << 4); \
    dst = *(const s16x8*)(Abuf + ar * 64 + (xo >> 1)); }
  #define LDB(dst, N, KS) { \
    int br = wn * 96 + (N) * 16 + l15; \
    int xo = ((KS) * 64 + lhi * 16) ^ ((br & 7) << 4); \
    dst = *(const s16x8*)(Bbuf + br * 64 + (xo >> 1)); }

  // prologue: A(0) reg-staged into buf0 (compiler waits on value use); B(0) gl_lds
  AISSUE(0);
  AWRITE(0);
  STAGE_B(0, 0);

  for (int t = 0; t < 14; t++){
    const unsigned short* Abuf = lds + (t & 1) * 8192;
    const unsigned short* Bbuf = ldsB + (t & 1) * 12288;
    int nA;
    if (t < 11){ AISSUE(t + 1); nA = 8; }
    else if (t < 13){ APBUF((t + 1) & 1, t + 1); nA = 4; }
    else nA = 0;
    // drain A(t)+B(t); keep A(t+1) issues in flight; flush own ds ops pre-barrier
    if (nA == 8)      asm volatile("s_waitcnt vmcnt(8) lgkmcnt(0)" ::: "memory");
    else if (nA == 4) asm volatile("s_waitcnt vmcnt(4) lgkmcnt(0)" ::: "memory");
    else              asm volatile("s_waitcnt vmcnt(0) lgkmcnt(0)" ::: "memory");
    __builtin_amdgcn_s_barrier();
    if (t < 13) STAGE_B((t + 1) & 1, t + 1);
    #pragma unroll
    for (int ks = 0; ks < 2; ks++){
      s16x8 bk[6], af[4];
      #pragma unroll
      for (int j = 0; j < 6; j++) LDB(bk[j], j, ks);
      #pragma unroll
      for (int j = 0; j < 4; j++) LDA(af[j], j, ks);
      __builtin_amdgcn_s_setprio(1);
      #pragma unroll
      for (int m = 0; m < 4; m++)
        #pragma unroll
        for (int n = 0; n < 6; n++)
          acc[m][n] = __builtin_amdgcn_mfma_f32_16x16x32_bf16(af[m], bk[n], acc[m][n], 0, 0, 0);
      __builtin_amdgcn_s_setprio(0);
    }
    if (t < 11){
      asm volatile("s_waitcnt vmcnt(6)" ::: "memory");   // A(t+1) f32 landed; 6 B in flight
      AWRITE((t + 1) & 1);
    }
  }
  #undef AISSUE
  #undef AWRITE
  #undef APBUF
  #undef STAGE_B
  #undef LDA
  #undef LDB

  // ---- epilogue: 2 stash rounds of 64 rows x 192 cols f32 (stride 196), coalesced ----
  __syncthreads();
  float* stf = (float*)lds;      // 64 x 196 x 4 = 50,176 B (dyn LDS = 57,344)
  float scale = *scalep;
  #pragma unroll
  for (int g = 0; g < 2; g++){
    if (wm == g){
      #pragma unroll
      for (int m = 0; m < 4; m++)
        #pragma unroll
        for (int n = 0; n < 6; n++)
          #pragma unroll
          for (int r = 0; r < 4; r++){
            int row = m * 16 + lhi * 4 + r;
            stf[row * 196 + wn * 96 + n * 16 + l15] = acc[m][n][r];
          }
    }
    __syncthreads();
    #pragma unroll
    for (int rp = 0; rp < 12; rp++){
      int idx = rp * 256 + tid;
      int row = idx / 48, c4 = idx - row * 48;
      int col = c4 * 4;
      long grow = brow + g * 64 + row;
      int gcol = bcol + col;
      f32x4 v = *(const f32x4*)(stf + row * 196 + col);
      f32x4 bias = *(const f32x4*)(bfv + gcol);
      f32x4 fb = *(const f32x4*)(xf + grow * 768 + gcol);   // true f32 residual
      f32x4 o;
      #pragma unroll
      for (int j = 0; j < 4; j++) o[j] = fb[j] + scale * (v[j] + bias[j]);
      *(f32x4*)(outf + grow * 768 + gcol) = o;
    }
    __syncthreads();
  }
}

extern "C" void kernel_launch(void* const* d_in, const int* in_sizes, int n_in,
                              void* d_out, int out_size, void* d_ws, size_t ws_size,
                              hipStream_t stream) {
  const float* x   = (const float*)d_in[0];
  const float* Wd  = (const float*)d_in[1];
  const float* bd  = (const float*)d_in[2];
  const float* Wu  = (const float*)d_in[3];
  const float* bu  = (const float*)d_in[4];
  const float* Wt  = (const float*)d_in[5];
  const float* bt  = (const float*)d_in[6];
  const float* Wf  = (const float*)d_in[7];
  const float* bfv = (const float*)d_in[8];
  const float* Ap  = (const float*)d_in[9];
  const float* Bp  = (const float*)d_in[10];
  const float* scalep = (const float*)d_in[11];
  const int* layerp   = (const int*)d_in[12];
  float* out = (float*)d_out;

  char* ws = (char*)d_ws;
  unsigned short* Pbuf    = (unsigned short*)(ws + 50331648);   //  8,388,608
  unsigned short* WB      = (unsigned short*)(ws + 58720256);   //  1,376,256 (768 x 896)
  unsigned short* Wtb     = (unsigned short*)(ws + 60096512);   //  1,179,648 (768 x 768)
  unsigned short* tokensb = (unsigned short*)(ws + 61276160);   //    172,032 (112 x 768)
  unsigned short* t2fb    = (unsigned short*)(ws + 61448192);   //    172,032 (112 x 768)
  unsigned short* Ab      = (unsigned short*)(ws + 61620224);   //     57,344 (112 x 256)
  unsigned short* Blb     = (unsigned short*)(ws + 61677568);   //    131,072 (256 x 256)
  unsigned short* Wdb     = (unsigned short*)(ws + 61808640);   //     49,152 ( 96 x 256)
  unsigned short* Wub     = (unsigned short*)(ws + 61857792);   //    147,456 (768 x  96)
  unsigned short* hb      = (unsigned short*)(ws + 62005248);   //     49,152 (256 x  96)
  unsigned short* Bfmt    = (unsigned short*)(ws + 62054400);   //    393,216 (768 x 256, Bf^T)

  const float* xf = x + 32 * 768;   // feats (skip cls rows)
  float* outf = out + 32 * 768;

  static int lds_attr_set = 0;
  if (!lds_attr_set){
    hipFuncSetAttribute((const void*)k_gemm, hipFuncAttributeMaxDynamicSharedMemorySize, 57344);
    lds_attr_set = 1;
  }

  k_prep<<<dim3(2688, 7), 256, 0, stream>>>(Wd, Wu, Wt, Wf, Ap, Bp, layerp, x, out,
                                            Wdb, Wub, Wtb, WB, Ab, Blb);
  k_mm<0><<<dim3(16, 6),  128, 0, stream>>>(Blb, 256, Wdb, 256, 256, bd, hb, 96);
  k_mm<1><<<dim3(16, 48), 128, 0, stream>>>(hb, 96, Wub, 96, 96, bu, Bfmt, 256);
  k_mm<2><<<dim3(7, 48),  128, 0, stream>>>(Ab, 256, Bfmt, 256, 256, nullptr, tokensb, 768);
  k_mm<2><<<dim3(7, 48),  128, 0, stream>>>(tokensb, 768, Wtb, 768, 768, bt, t2fb, 768);
  k_mm<3><<<dim3(7, 48),  128, 0, stream>>>(t2fb, 768, WB, 896, 768, nullptr, WB, 0);

  k_attn<<<1024, 256, 0, stream>>>(xf, tokensb, Pbuf);
  k_gemm<<<1024, 256, 57344, stream>>>(xf, Pbuf, WB, bfv, scalep, outf);
}